// Round 1
// baseline (15027.838 us; speedup 1.0000x reference)
//
#include <hip/hip_runtime.h>
#include <hip/hip_bf16.h>

#define DIM 192
#define HEADS 6
#define HD 32
#define WS 12
#define N_TOK 144      // 12*12
#define HIMG 256
#define WIMG 256
#define NH 22
#define NW 22
#define NWIN (4*NH*NW) // 1936
#define SCALE 0.17677669529663687f  // 32^-0.5

__global__ __launch_bounds__(256) void wsa_kernel(
    const float* __restrict__ x,
    const float* __restrict__ w_qkv,
    const float* __restrict__ w_proj,
    float* __restrict__ out)
{
    // [c][t] layouts so lane-consecutive t => contiguous LDS (conflict-free)
    __shared__ __hip_bfloat16 x_lds[DIM][N_TOK];    // 55,296 B
    __shared__ __hip_bfloat16 ao_lds[DIM][N_TOK];   // 55,296 B
    __shared__ __hip_bfloat16 q_lds[N_TOK][HD + 2]; // 9,792 B (stride 34 -> t*17 dwords, spreads banks)
    __shared__ __hip_bfloat16 k_lds[N_TOK][HD + 2];
    __shared__ __hip_bfloat16 v_lds[N_TOK][HD + 2];

    const int tid = threadIdx.x;
    const int wid = blockIdx.x;
    const int b  = wid / (NH * NW);
    const int r0 = wid % (NH * NW);
    const int wh = r0 / NW;
    const int ww = r0 % NW;

    // ---- Phase 1: gather window (with reflect pad) into LDS as bf16 ----
    for (int idx = tid; idx < DIM * N_TOK; idx += 256) {
        const int c = idx / N_TOK;
        const int t = idx % N_TOK;
        const int ty = t / WS, tx = t % WS;
        int h = wh * WS + ty; if (h >= HIMG) h = 2 * HIMG - 2 - h;
        int w = ww * WS + tx; if (w >= WIMG) w = 2 * WIMG - 2 - w;
        const float val = x[((size_t)(b * DIM + c) * HIMG + h) * WIMG + w];
        x_lds[c][t] = __float2bfloat16(val);
    }
    __syncthreads();

    for (int hh = 0; hh < HEADS; ++hh) {
        // ---- qkv for this head: 96 rows (q32,k32,v32) x 144 tokens ----
        for (int idx = tid; idx < 96 * N_TOK; idx += 256) {
            const int r = idx / N_TOK;   // 0..95
            const int t = idx % N_TOK;
            const int kind = r >> 5;     // 0=q, 1=k, 2=v
            const int j = r & 31;
            const int row = kind * DIM + hh * HD + j;
            const float* __restrict__ wrow = w_qkv + (size_t)row * DIM;
            float acc = 0.f;
            #pragma unroll 4
            for (int c = 0; c < DIM; ++c)
                acc += __bfloat162float(x_lds[c][t]) * wrow[c];
            if (kind == 0)      q_lds[t][j] = __float2bfloat16(acc * SCALE);
            else if (kind == 1) k_lds[t][j] = __float2bfloat16(acc);
            else                v_lds[t][j] = __float2bfloat16(acc);
        }
        __syncthreads();

        // ---- attention: coset-sparse (15 valid keys per query) ----
        if (tid < N_TOK) {
            const int t = tid;
            const int ti = t / WS, tj = t % WS;
            const int ci = ti % 3, cj = tj % 3;
            float q[HD];
            #pragma unroll
            for (int j = 0; j < HD; ++j) q[j] = __bfloat162float(q_lds[t][j]);

            float s[16];
            float m = -1e30f;
            #pragma unroll
            for (int n = 0; n < 16; ++n) {
                const int ui = ci + 3 * (n >> 2);
                const int uj = cj + 3 * (n & 3);
                const int u = ui * WS + uj;
                if (u == t) { s[n] = -1e30f; continue; }
                float acc = 0.f;
                #pragma unroll
                for (int j = 0; j < HD; ++j)
                    acc += q[j] * __bfloat162float(k_lds[u][j]);
                s[n] = acc;
                m = fmaxf(m, acc);
            }
            float p[16];
            float psum = 0.f;
            #pragma unroll
            for (int n = 0; n < 16; ++n) {
                float e = __expf(s[n] - m);
                if (s[n] <= -1e29f) e = 0.f;   // self
                p[n] = e;
                psum += e;
            }
            const float inv = 1.f / psum;

            float o[HD];
            #pragma unroll
            for (int j = 0; j < HD; ++j) o[j] = 0.f;
            #pragma unroll
            for (int n = 0; n < 16; ++n) {
                const int ui = ci + 3 * (n >> 2);
                const int uj = cj + 3 * (n & 3);
                const int u = ui * WS + uj;
                const float pn = p[n];
                #pragma unroll
                for (int j = 0; j < HD; ++j)
                    o[j] += pn * __bfloat162float(v_lds[u][j]);
            }
            #pragma unroll
            for (int j = 0; j < HD; ++j)
                ao_lds[hh * HD + j][t] = __float2bfloat16(o[j] * inv);
        }
        __syncthreads();
    }

    // ---- proj + window-merge with crop ----
    for (int idx = tid; idx < DIM * N_TOK; idx += 256) {
        const int oc = idx / N_TOK;
        const int t = idx % N_TOK;
        const int ty = t / WS, tx = t % WS;
        const int h = wh * WS + ty;
        const int w = ww * WS + tx;
        if (h >= HIMG || w >= WIMG) continue;
        const float* __restrict__ wrow = w_proj + (size_t)oc * DIM;
        float acc = 0.f;
        #pragma unroll 4
        for (int c = 0; c < DIM; ++c)
            acc += __bfloat162float(ao_lds[c][t]) * wrow[c];
        out[((size_t)(b * DIM + oc) * HIMG + h) * WIMG + w] = acc;
    }
}

extern "C" void kernel_launch(void* const* d_in, const int* in_sizes, int n_in,
                              void* d_out, int out_size, void* d_ws, size_t ws_size,
                              hipStream_t stream) {
    const float* x      = (const float*)d_in[0];
    const float* w_qkv  = (const float*)d_in[1];
    const float* w_proj = (const float*)d_in[2];
    float* out = (float*)d_out;
    wsa_kernel<<<dim3(NWIN), dim3(256), 0, stream>>>(x, w_qkv, w_proj, out);
}

// Round 2
// 455.006 us; speedup vs baseline: 33.0278x; 33.0278x over previous
//
#include <hip/hip_runtime.h>
#include <hip/hip_bf16.h>

typedef __bf16 bf16x8 __attribute__((ext_vector_type(8)));
typedef float f32x4 __attribute__((ext_vector_type(4)));
typedef unsigned int u32x4 __attribute__((ext_vector_type(4)));

#define HEADS 6
#define WS 12
#define NTOK 144
#define RES 256
#define NHW 22
#define NWIN (4*NHW*NHW)
#define SCALE 0.17677669529663687f
#define XS 200   // x row stride (bf16): 400 B, 16B-aligned, bank step 4
#define QS 40    // q/k/v row stride (bf16): 80 B, 16B-aligned

static __device__ __forceinline__ unsigned f2u(float f) {
    return (unsigned)__builtin_bit_cast(unsigned short, __float2bfloat16(f));
}
static __device__ __forceinline__ unsigned pk2(float a, float b) {
    return f2u(a) | (f2u(b) << 16);
}
static __device__ __forceinline__ bf16x8 ld8(const void* p) {
    return *(const bf16x8*)p;
}
// load 8 consecutive fp32 weights -> bf16x8 fragment
static __device__ __forceinline__ bf16x8 wfrag(const float* p) {
    const float4* p4 = (const float4*)p;
    float4 lo = p4[0], hi = p4[1];
    u32x4 u = { pk2(lo.x, lo.y), pk2(lo.z, lo.w), pk2(hi.x, hi.y), pk2(hi.z, hi.w) };
    return __builtin_bit_cast(bf16x8, u);
}

__global__ __launch_bounds__(384) void wsa_kernel(
    const float* __restrict__ x,
    const float* __restrict__ w_qkv,
    const float* __restrict__ w_proj,
    float* __restrict__ out)
{
    __shared__ __align__(16) unsigned char smem[57600 + 3 * 11520]; // 92,160 B
    __hip_bfloat16 (* const xw)[XS] = reinterpret_cast<__hip_bfloat16(*)[XS]>(smem);
    float          (* const stg)[100] = reinterpret_cast<float(*)[100]>(smem); // aliases xw (dead)
    __hip_bfloat16 (* const qL)[QS] = reinterpret_cast<__hip_bfloat16(*)[QS]>(smem + 57600);
    __hip_bfloat16 (* const kL)[QS] = reinterpret_cast<__hip_bfloat16(*)[QS]>(smem + 57600 + 11520);
    __hip_bfloat16 (* const vL)[QS] = reinterpret_cast<__hip_bfloat16(*)[QS]>(smem + 57600 + 23040);

    const int tid  = threadIdx.x;
    const int lane = tid & 63;
    const int wv   = tid >> 6;      // wave 0..5
    const int col  = lane & 15;
    const int grp  = lane >> 4;     // 0..3

    const int wid = blockIdx.x;
    const int b   = wid / (NHW * NHW);
    const int r0  = wid % (NHW * NHW);
    const int wh  = r0 / NHW;
    const int ww  = r0 % NHW;

    // ---- stage x window (reflect pad) into LDS bf16 [t][c], b128 writes ----
    #pragma unroll
    for (int it = 0; it < 9; ++it) {
        int u  = tid + it * 384;          // u = c8*144 + t  (t fastest -> coalesced)
        int c8 = u / NTOK;
        int t  = u - c8 * NTOK;
        int ty = t / WS, tx = t - ty * WS;
        int h = wh * WS + ty; if (h >= RES) h = 2 * RES - 2 - h;
        int w = ww * WS + tx; if (w >= RES) w = 2 * RES - 2 - w;
        const float* px = x + ((size_t)(b * 192 + c8 * 8) * RES + h) * RES + w;
        u32x4 uv;
        #pragma unroll
        for (int j = 0; j < 4; ++j)
            uv[j] = pk2(px[(size_t)(2 * j) * RES * RES], px[(size_t)(2 * j + 1) * RES * RES]);
        *(u32x4*)&xw[t][c8 * 8] = uv;
    }
    __syncthreads();

    f32x4 pacc[2][9];   // persistent proj accumulators: nt = wv, wv+6
    #pragma unroll
    for (int i = 0; i < 2; ++i)
        #pragma unroll
        for (int m = 0; m < 9; ++m)
            pacc[i][m] = (f32x4){0.f, 0.f, 0.f, 0.f};

    for (int hh = 0; hh < HEADS; ++hh) {
        // ---- qkv GEMM: wave wv owns n-tile wv (96 cols of this head) ----
        {
            const int kind  = wv >> 1;            // 0=q 1=k 2=v
            const int dbase = (wv & 1) * 16;
            const int rg    = kind * 192 + hh * 32 + dbase + col;
            bf16x8 Bf[6];
            #pragma unroll
            for (int k0 = 0; k0 < 6; ++k0)
                Bf[k0] = wfrag(w_qkv + (size_t)rg * 192 + k0 * 32 + grp * 8);
            __hip_bfloat16 (* const dst)[QS] = (kind == 0) ? qL : (kind == 1) ? kL : vL;
            const float qs = (kind == 0) ? SCALE : 1.f;
            for (int mt0 = 0; mt0 < 9; mt0 += 3) {
                f32x4 a0 = {0.f,0.f,0.f,0.f}, a1 = a0, a2 = a0;
                #pragma unroll
                for (int k0 = 0; k0 < 6; ++k0) {
                    bf16x8 A0 = ld8(&xw[(mt0 + 0) * 16 + col][k0 * 32 + grp * 8]);
                    bf16x8 A1 = ld8(&xw[(mt0 + 1) * 16 + col][k0 * 32 + grp * 8]);
                    bf16x8 A2 = ld8(&xw[(mt0 + 2) * 16 + col][k0 * 32 + grp * 8]);
                    a0 = __builtin_amdgcn_mfma_f32_16x16x32_bf16(A0, Bf[k0], a0, 0, 0, 0);
                    a1 = __builtin_amdgcn_mfma_f32_16x16x32_bf16(A1, Bf[k0], a1, 0, 0, 0);
                    a2 = __builtin_amdgcn_mfma_f32_16x16x32_bf16(A2, Bf[k0], a2, 0, 0, 0);
                }
                #pragma unroll
                for (int r = 0; r < 4; ++r) {
                    dst[(mt0 + 0) * 16 + grp * 4 + r][dbase + col] = __float2bfloat16(a0[r] * qs);
                    dst[(mt0 + 1) * 16 + grp * 4 + r][dbase + col] = __float2bfloat16(a1[r] * qs);
                    dst[(mt0 + 2) * 16 + grp * 4 + r][dbase + col] = __float2bfloat16(a2[r] * qs);
                }
            }
        }
        __syncthreads();

        // ---- coset attention: wave wv handles cosets wv (+6) ----
        for (int cs = wv; cs < 9; cs += 6) {
            const int ci = cs / 3, cj = cs % 3;
            const int tcol = (ci + 3 * (col >> 2)) * WS + cj + 3 * (col & 3); // token for m/n = col
            bf16x8 Kf = ld8(&kL[tcol][grp * 8]);
            bf16x8 Qf = ld8(&qL[tcol][grp * 8]);
            f32x4 S = {0.f,0.f,0.f,0.f};
            S = __builtin_amdgcn_mfma_f32_16x16x32_bf16(Kf, Qf, S, 0, 0, 0);
            // lane holds S^T: key m = grp*4+r, query n = col
            float e[4]; float mx = -1e30f;
            #pragma unroll
            for (int r = 0; r < 4; ++r) {
                float s = (grp * 4 + r == col) ? -1e30f : S[r];   // self mask
                e[r] = s;
                mx = fmaxf(mx, s);
            }
            mx = fmaxf(mx, __shfl_xor(mx, 16));
            mx = fmaxf(mx, __shfl_xor(mx, 32));
            float sum = 0.f;
            #pragma unroll
            for (int r = 0; r < 4; ++r) { e[r] = __expf(e[r] - mx); sum += e[r]; }
            sum += __shfl_xor(sum, 16);
            sum += __shfl_xor(sum, 32);
            const float inv = 1.f / sum;
            const unsigned w0 = pk2(e[0] * inv, e[1] * inv);
            const unsigned w1 = pk2(e[2] * inv, e[3] * inv);
            // redistribute P -> A-fragment (row n, k=m) via bpermute; lanes grp>=2 are k>=16 pad
            u32x4 pa = {0u, 0u, 0u, 0u};
            {
                const int sA = (col + 32 * grp) * 4;
                int q0 = __builtin_amdgcn_ds_bpermute(sA,      (int)w0);
                int q1 = __builtin_amdgcn_ds_bpermute(sA,      (int)w1);
                int q2 = __builtin_amdgcn_ds_bpermute(sA + 64, (int)w0);
                int q3 = __builtin_amdgcn_ds_bpermute(sA + 64, (int)w1);
                if (grp < 2) pa = (u32x4){(unsigned)q0, (unsigned)q1, (unsigned)q2, (unsigned)q3};
            }
            const bf16x8 PA = __builtin_bit_cast(bf16x8, pa);
            #pragma unroll
            for (int d0 = 0; d0 < 2; ++d0) {
                u32x4 vb = {0u, 0u, 0u, 0u};
                if (grp < 2) {
                    #pragma unroll
                    for (int j = 0; j < 8; j += 2) {
                        int m0 = grp * 8 + j, m1 = m0 + 1;
                        int t0 = (ci + 3 * (m0 >> 2)) * WS + cj + 3 * (m0 & 3);
                        int t1 = (ci + 3 * (m1 >> 2)) * WS + cj + 3 * (m1 & 3);
                        unsigned a = __builtin_bit_cast(unsigned short, vL[t0][d0 * 16 + col]);
                        unsigned bb = __builtin_bit_cast(unsigned short, vL[t1][d0 * 16 + col]);
                        vb[j >> 1] = a | (bb << 16);
                    }
                }
                bf16x8 VB = __builtin_bit_cast(bf16x8, vb);
                f32x4 O = {0.f,0.f,0.f,0.f};
                O = __builtin_amdgcn_mfma_f32_16x16x32_bf16(PA, VB, O, 0, 0, 0);
                #pragma unroll
                for (int r = 0; r < 4; ++r) {
                    int n = grp * 4 + r;
                    int t = (ci + 3 * (n >> 2)) * WS + cj + 3 * (n & 3);
                    qL[t][d0 * 16 + col] = __float2bfloat16(O[r]);  // ao for this head (coset rows disjoint)
                }
            }
        }
        __syncthreads();

        // ---- partial proj: K=32 (this head); wave owns oc-tiles wv and wv+6 ----
        {
            bf16x8 B0 = wfrag(w_proj + (size_t)(wv * 16 + col) * 192 + hh * 32 + grp * 8);
            bf16x8 B1 = wfrag(w_proj + (size_t)((wv + 6) * 16 + col) * 192 + hh * 32 + grp * 8);
            #pragma unroll
            for (int mt = 0; mt < 9; ++mt) {
                bf16x8 A = ld8(&qL[mt * 16 + col][grp * 8]);
                pacc[0][mt] = __builtin_amdgcn_mfma_f32_16x16x32_bf16(A, B0, pacc[0][mt], 0, 0, 0);
                pacc[1][mt] = __builtin_amdgcn_mfma_f32_16x16x32_bf16(A, B1, pacc[1][mt], 0, 0, 0);
            }
        }
        __syncthreads();
    }

    // ---- output: stage f32 in (dead) x region, coalesced write, two oc-halves ----
    for (int half = 0; half < 2; ++half) {
        __syncthreads();
        #pragma unroll
        for (int mt = 0; mt < 9; ++mt)
            #pragma unroll
            for (int r = 0; r < 4; ++r)
                stg[mt * 16 + grp * 4 + r][wv * 16 + col] = pacc[half][mt][r];
        __syncthreads();
        const int txo = tid % 12;
        const int u0  = tid / 12;    // 0..31
        for (int it = 0; it < 36; ++it) {
            int u = u0 + it * 32;            // u = oc_l*12 + ty
            int oc_l = u / 12, ty = u % 12;
            int h = wh * WS + ty, w = ww * WS + txo;
            if (h < RES && w < RES)
                out[((size_t)(b * 192 + half * 96 + oc_l) * RES + h) * RES + w] = stg[ty * WS + txo][oc_l];
        }
    }
}

extern "C" void kernel_launch(void* const* d_in, const int* in_sizes, int n_in,
                              void* d_out, int out_size, void* d_ws, size_t ws_size,
                              hipStream_t stream) {
    const float* x      = (const float*)d_in[0];
    const float* w_qkv  = (const float*)d_in[1];
    const float* w_proj = (const float*)d_in[2];
    float* out = (float*)d_out;
    wsa_kernel<<<dim3(NWIN), dim3(384), 0, stream>>>(x, w_qkv, w_proj, out);
}

// Round 3
// 360.685 us; speedup vs baseline: 41.6648x; 1.2615x over previous
//
#include <hip/hip_runtime.h>
#include <hip/hip_bf16.h>

typedef __bf16 bf16x8 __attribute__((ext_vector_type(8)));
typedef float f32x4 __attribute__((ext_vector_type(4)));
typedef unsigned int u32x4 __attribute__((ext_vector_type(4)));

#define HEADS 6
#define WS 12
#define NTOK 144
#define RES 256
#define NHW 22
#define NWIN (4*NHW*NHW)
#define SCALE 0.17677669529663687f
#define XS 200   // x row stride (bf16): 400 B
#define QS 40    // q/k/v row stride (bf16): 80 B

static __device__ __forceinline__ unsigned f2u(float f) {
    return (unsigned)__builtin_bit_cast(unsigned short, __float2bfloat16(f));
}
static __device__ __forceinline__ unsigned pk2(float a, float b) {
    return f2u(a) | (f2u(b) << 16);
}
static __device__ __forceinline__ bf16x8 ld8(const void* p) {
    return *(const bf16x8*)p;
}
static __device__ __forceinline__ bf16x8 wfrag(const float* p) {
    const float4* p4 = (const float4*)p;
    float4 lo = p4[0], hi = p4[1];
    u32x4 u = { pk2(lo.x, lo.y), pk2(lo.z, lo.w), pk2(hi.x, hi.y), pk2(hi.z, hi.w) };
    return __builtin_bit_cast(bf16x8, u);
}

__global__ __launch_bounds__(768) void wsa_kernel(
    const float* __restrict__ x,
    const float* __restrict__ w_qkv,
    const float* __restrict__ w_proj,
    float* __restrict__ out)
{
    // 57,600 (x window) + 6 * 11,520 (q/k/v for 2 heads) = 126,720 B -> 1 block/CU, 12 waves
    __shared__ __align__(16) unsigned char smem[57600 + 6 * 11520];
    __hip_bfloat16 (* const xw)[XS] = reinterpret_cast<__hip_bfloat16(*)[XS]>(smem);
    float          (* const stg)[100] = reinterpret_cast<float(*)[100]>(smem); // aliases xw (dead in epilogue)
    // plane index = kind*2 + h2  (kind 0=q 1=k 2=v; h2 = head within pair)
    __hip_bfloat16 (* const qkvL)[NTOK][QS] =
        reinterpret_cast<__hip_bfloat16(*)[NTOK][QS]>(smem + 57600);

    const int tid  = threadIdx.x;
    const int lane = tid & 63;
    const int wv   = tid >> 6;      // wave 0..11
    const int col  = lane & 15;
    const int grp  = lane >> 4;     // 0..3

    const int wid = blockIdx.x;
    const int b   = wid / (NHW * NHW);
    const int r0  = wid % (NHW * NHW);
    const int wh  = r0 / NHW;
    const int ww  = r0 % NHW;

    // ---- stage x window (reflect pad) into LDS bf16 [t][c] ----
    for (int u = tid; u < 24 * NTOK; u += 768) {   // u = c8*144 + t
        int c8 = u / NTOK;
        int t  = u - c8 * NTOK;
        int ty = t / WS, tx = t - ty * WS;
        int h = wh * WS + ty; if (h >= RES) h = 2 * RES - 2 - h;
        int w = ww * WS + tx; if (w >= RES) w = 2 * RES - 2 - w;
        const float* px = x + ((size_t)(b * 192 + c8 * 8) * RES + h) * RES + w;
        u32x4 uv;
        #pragma unroll
        for (int j = 0; j < 4; ++j)
            uv[j] = pk2(px[(size_t)(2 * j) * RES * RES], px[(size_t)(2 * j + 1) * RES * RES]);
        *(u32x4*)&xw[t][c8 * 8] = uv;
    }
    __syncthreads();

    f32x4 pacc[9];   // persistent proj accumulators; wave owns oc-tile wv (16 cols)
    #pragma unroll
    for (int m = 0; m < 9; ++m) pacc[m] = (f32x4){0.f, 0.f, 0.f, 0.f};

    for (int hp = 0; hp < 3; ++hp) {               // head pair
        // ---- qkv GEMM for 2 heads: wave -> (h2, kind, dhalf) ----
        {
            const int h2    = wv / 6;
            const int sub   = wv % 6;
            const int kind  = sub >> 1;            // 0=q 1=k 2=v
            const int dbase = (sub & 1) * 16;
            const int hh    = hp * 2 + h2;
            const int rg    = kind * 192 + hh * 32 + dbase + col;
            bf16x8 Bf[6];
            #pragma unroll
            for (int k0 = 0; k0 < 6; ++k0)
                Bf[k0] = wfrag(w_qkv + (size_t)rg * 192 + k0 * 32 + grp * 8);
            __hip_bfloat16 (* const dst)[QS] = qkvL[kind * 2 + h2];
            const float qs = (kind == 0) ? SCALE : 1.f;
            for (int mt0 = 0; mt0 < 9; mt0 += 3) {
                f32x4 a0 = {0.f,0.f,0.f,0.f}, a1 = a0, a2 = a0;
                #pragma unroll
                for (int k0 = 0; k0 < 6; ++k0) {
                    bf16x8 A0 = ld8(&xw[(mt0 + 0) * 16 + col][k0 * 32 + grp * 8]);
                    bf16x8 A1 = ld8(&xw[(mt0 + 1) * 16 + col][k0 * 32 + grp * 8]);
                    bf16x8 A2 = ld8(&xw[(mt0 + 2) * 16 + col][k0 * 32 + grp * 8]);
                    a0 = __builtin_amdgcn_mfma_f32_16x16x32_bf16(A0, Bf[k0], a0, 0, 0, 0);
                    a1 = __builtin_amdgcn_mfma_f32_16x16x32_bf16(A1, Bf[k0], a1, 0, 0, 0);
                    a2 = __builtin_amdgcn_mfma_f32_16x16x32_bf16(A2, Bf[k0], a2, 0, 0, 0);
                }
                #pragma unroll
                for (int r = 0; r < 4; ++r) {
                    dst[(mt0 + 0) * 16 + grp * 4 + r][dbase + col] = __float2bfloat16(a0[r] * qs);
                    dst[(mt0 + 1) * 16 + grp * 4 + r][dbase + col] = __float2bfloat16(a1[r] * qs);
                    dst[(mt0 + 2) * 16 + grp * 4 + r][dbase + col] = __float2bfloat16(a2[r] * qs);
                }
            }
        }
        __syncthreads();

        // ---- coset attention: 18 tasks (h2, coset) over 12 waves ----
        for (int u = wv; u < 18; u += 12) {
            const int h2 = u / 9;
            const int cs = u % 9;
            __hip_bfloat16 (* const qP)[QS] = qkvL[0 * 2 + h2];
            __hip_bfloat16 (* const kP)[QS] = qkvL[1 * 2 + h2];
            __hip_bfloat16 (* const vP)[QS] = qkvL[2 * 2 + h2];
            const int ci = cs / 3, cj = cs % 3;
            const int tcol = (ci + 3 * (col >> 2)) * WS + cj + 3 * (col & 3);
            bf16x8 Kf = ld8(&kP[tcol][grp * 8]);
            bf16x8 Qf = ld8(&qP[tcol][grp * 8]);
            f32x4 S = {0.f,0.f,0.f,0.f};
            S = __builtin_amdgcn_mfma_f32_16x16x32_bf16(Kf, Qf, S, 0, 0, 0);
            // lane holds S^T: key m = grp*4+r, query n = col
            float e[4]; float mx = -1e30f;
            #pragma unroll
            for (int r = 0; r < 4; ++r) {
                float s = (grp * 4 + r == col) ? -1e30f : S[r];
                e[r] = s;
                mx = fmaxf(mx, s);
            }
            mx = fmaxf(mx, __shfl_xor(mx, 16));
            mx = fmaxf(mx, __shfl_xor(mx, 32));
            float sum = 0.f;
            #pragma unroll
            for (int r = 0; r < 4; ++r) { e[r] = __expf(e[r] - mx); sum += e[r]; }
            sum += __shfl_xor(sum, 16);
            sum += __shfl_xor(sum, 32);
            const float inv = 1.f / sum;
            const unsigned w0 = pk2(e[0] * inv, e[1] * inv);
            const unsigned w1 = pk2(e[2] * inv, e[3] * inv);
            u32x4 pa = {0u, 0u, 0u, 0u};
            {
                const int sA = (col + 32 * grp) * 4;
                int q0 = __builtin_amdgcn_ds_bpermute(sA,      (int)w0);
                int q1 = __builtin_amdgcn_ds_bpermute(sA,      (int)w1);
                int q2 = __builtin_amdgcn_ds_bpermute(sA + 64, (int)w0);
                int q3 = __builtin_amdgcn_ds_bpermute(sA + 64, (int)w1);
                if (grp < 2) pa = (u32x4){(unsigned)q0, (unsigned)q1, (unsigned)q2, (unsigned)q3};
            }
            const bf16x8 PA = __builtin_bit_cast(bf16x8, pa);
            #pragma unroll
            for (int d0 = 0; d0 < 2; ++d0) {
                u32x4 vb = {0u, 0u, 0u, 0u};
                if (grp < 2) {
                    #pragma unroll
                    for (int j = 0; j < 8; j += 2) {
                        int m0 = grp * 8 + j, m1 = m0 + 1;
                        int t0 = (ci + 3 * (m0 >> 2)) * WS + cj + 3 * (m0 & 3);
                        int t1 = (ci + 3 * (m1 >> 2)) * WS + cj + 3 * (m1 & 3);
                        unsigned a  = __builtin_bit_cast(unsigned short, vP[t0][d0 * 16 + col]);
                        unsigned bb = __builtin_bit_cast(unsigned short, vP[t1][d0 * 16 + col]);
                        vb[j >> 1] = a | (bb << 16);
                    }
                }
                bf16x8 VB = __builtin_bit_cast(bf16x8, vb);
                f32x4 O = {0.f,0.f,0.f,0.f};
                O = __builtin_amdgcn_mfma_f32_16x16x32_bf16(PA, VB, O, 0, 0, 0);
                #pragma unroll
                for (int r = 0; r < 4; ++r) {
                    int n = grp * 4 + r;
                    int t = (ci + 3 * (n >> 2)) * WS + cj + 3 * (n & 3);
                    qP[t][d0 * 16 + col] = __float2bfloat16(O[r]);  // ao (coset rows disjoint)
                }
            }
        }
        __syncthreads();

        // ---- partial proj: K=64 (this head pair); wave owns oc-tile wv ----
        {
            #pragma unroll
            for (int h2 = 0; h2 < 2; ++h2) {
                const int hh = hp * 2 + h2;
                bf16x8 Bp = wfrag(w_proj + (size_t)(wv * 16 + col) * 192 + hh * 32 + grp * 8);
                __hip_bfloat16 (* const aoP)[QS] = qkvL[0 * 2 + h2];
                #pragma unroll
                for (int mt = 0; mt < 9; ++mt) {
                    bf16x8 A = ld8(&aoP[mt * 16 + col][grp * 8]);
                    pacc[mt] = __builtin_amdgcn_mfma_f32_16x16x32_bf16(A, Bp, pacc[mt], 0, 0, 0);
                }
            }
        }
        __syncthreads();
    }

    // ---- output: stage f32 in (dead) x region, coalesced write, two oc-halves ----
    for (int half = 0; half < 2; ++half) {
        __syncthreads();
        if (wv >= half * 6 && wv < half * 6 + 6) {
            const int ocl = (wv - half * 6) * 16 + col;   // 0..95
            #pragma unroll
            for (int mt = 0; mt < 9; ++mt)
                #pragma unroll
                for (int r = 0; r < 4; ++r)
                    stg[mt * 16 + grp * 4 + r][ocl] = pacc[mt][r];
        }
        __syncthreads();
        const int txo = tid % 12;
        const int u0  = tid / 12;    // 0..63
        for (int it = 0; it < 18; ++it) {
            int u = u0 + it * 64;            // u = oc_l*12 + ty
            int oc_l = u / 12, ty = u % 12;
            int h = wh * WS + ty, w = ww * WS + txo;
            if (h < RES && w < RES)
                out[((size_t)(b * 192 + half * 96 + oc_l) * RES + h) * RES + w] = stg[ty * WS + txo][oc_l];
        }
    }
}

extern "C" void kernel_launch(void* const* d_in, const int* in_sizes, int n_in,
                              void* d_out, int out_size, void* d_ws, size_t ws_size,
                              hipStream_t stream) {
    const float* x      = (const float*)d_in[0];
    const float* w_qkv  = (const float*)d_in[1];
    const float* w_proj = (const float*)d_in[2];
    float* out = (float*)d_out;
    wsa_kernel<<<dim3(NWIN), dim3(768), 0, stream>>>(x, w_qkv, w_proj, out);
}